// Round 15
// baseline (289.388 us; speedup 1.0000x reference)
//
#include <hip/hip_runtime.h>

#define B_ 32
#define N_ 16384
#define K_ 16
#define P_ 120
#define CH_ 32          // chunks per (b) row
#define PTS 512         // points per chunk
#define ITERS 8         // PTS / 64 points-per-block-iteration
#define YPAD 514        // 512+2: store bank = (8q+2kk+u)%32 -> 2 lanes/bank (free)
#define NBLK (CH_ * B_) // 1024 spin participants

// ============ k1: single-sweep softmax (spin-barrier), KPA+KPCD+GFP ============
// Phase A: ev=exp(KP·W) -> LDS ybuf (+chunk sums -> parts2, block-private 128B lines).
// Device-wide ticket barrier (all 1024 blocks co-resident by construction:
// launch_bounds(256,4) caps VGPR<=128 and LDS 35KB<=40KB -> 4 blocks/CU x 256 CU = 1024).
// Phase B: S (f64 fixed order), scale-on-read -> coalesced KPA write + KPCD partials.
__global__ __launch_bounds__(256, 4) void k_fused(const float* __restrict__ KP,
                                                  const float* __restrict__ W,
                                                  const float* __restrict__ X,
                                                  float* __restrict__ out_kpa,
                                                  float* __restrict__ parts2,
                                                  float* __restrict__ kpcdpart,
                                                  const float* __restrict__ GF,
                                                  float* __restrict__ gfp,
                                                  int* __restrict__ cnt) {
    __shared__ float pool[16 * YPAD];        // 32896 B: unnormalized ev tile
    __shared__ float Wl[256];
    __shared__ float iSs[16];
    __shared__ float ss[4][4][4];
    __shared__ float sa[4][4][4][3];
    int bid = blockIdx.x, t = threadIdx.x;
    int ch = bid & (CH_ - 1), b = bid >> 5;
    int w = t >> 6, q = t & 3;
    float (*ybuf)[YPAD] = (float(*)[YPAD])pool;
    Wl[t] = W[t];
    __syncthreads();
    float Wr[4][4][4];                       // [m][jj][kk] : W[4(q^m)+jj][4q+kk]
#pragma unroll
    for (int m = 0; m < 4; ++m)
#pragma unroll
        for (int jj = 0; jj < 4; ++jj)
#pragma unroll
            for (int kk = 0; kk < 4; ++kk)
                Wr[m][jj][kk] = Wl[(4 * (q ^ m) + jj) * 16 + 4 * q + kk];
    const float4* KP4 = (const float4*)KP;
    size_t base = (size_t)b * (N_ * 4) + (size_t)ch * (PTS * 4);
    float s4[4] = {0.0f, 0.0f, 0.0f, 0.0f};
#pragma unroll
    for (int it = 0; it < ITERS; ++it) {
        float4 a = KP4[base + it * 256 + t];
        float c0 = __shfl_xor(a.x, 1), c1 = __shfl_xor(a.y, 1), c2 = __shfl_xor(a.z, 1), c3 = __shfl_xor(a.w, 1);
        float d0 = __shfl_xor(a.x, 2), d1 = __shfl_xor(a.y, 2), d2 = __shfl_xor(a.z, 2), d3 = __shfl_xor(a.w, 2);
        float e0 = __shfl_xor(a.x, 3), e1 = __shfl_xor(a.y, 3), e2 = __shfl_xor(a.z, 3), e3 = __shfl_xor(a.w, 3);
        int nloc = it * 64 + (t >> 2);
#pragma unroll
        for (int kk = 0; kk < 4; ++kk) {
            float v = a.x * Wr[0][0][kk];
            v = fmaf(a.y, Wr[0][1][kk], v); v = fmaf(a.z, Wr[0][2][kk], v); v = fmaf(a.w, Wr[0][3][kk], v);
            v = fmaf(c0, Wr[1][0][kk], v);  v = fmaf(c1, Wr[1][1][kk], v);
            v = fmaf(c2, Wr[1][2][kk], v);  v = fmaf(c3, Wr[1][3][kk], v);
            v = fmaf(d0, Wr[2][0][kk], v);  v = fmaf(d1, Wr[2][1][kk], v);
            v = fmaf(d2, Wr[2][2][kk], v);  v = fmaf(d3, Wr[2][3][kk], v);
            v = fmaf(e0, Wr[3][0][kk], v);  v = fmaf(e1, Wr[3][1][kk], v);
            v = fmaf(e2, Wr[3][2][kk], v);  v = fmaf(e3, Wr[3][3][kk], v);
            float ev = expf(v);
            ybuf[4 * q + kk][nloc] = ev;     // unnormalized, lives across the barrier
            s4[kk] += ev;
        }
    }
#pragma unroll
    for (int o = 4; o <= 32; o <<= 1)
#pragma unroll
        for (int kk = 0; kk < 4; ++kk) s4[kk] += __shfl_xor(s4[kk], o);
    if ((t & 63) < 4)
#pragma unroll
        for (int kk = 0; kk < 4; ++kk) ss[w][q][kk] = s4[kk];
    __syncthreads();
    if (t < 16) {                            // k = t; 64B write in a private 128B line
        int qq = t >> 2, kk = t & 3;
        parts2[(size_t)bid * 32 + t] =
            ss[0][qq][kk] + ss[1][qq][kk] + ss[2][qq][kk] + ss[3][qq][kk];
    }
    if (bid < 128) {                         // GFP side work absorbed by barrier slack
        int i = bid * 256 + t;
        const float4* g = (const float4*)(GF + (size_t)i * 16);
        float4 a = g[0], b4 = g[1], c = g[2], d = g[3];
        float m = fmaxf(fmaxf(fmaxf(a.x, a.y), fmaxf(a.z, a.w)),
                        fmaxf(fmaxf(b4.x, b4.y), fmaxf(b4.z, b4.w)));
        m = fmaxf(m, fmaxf(fmaxf(c.x, c.y), fmaxf(c.z, c.w)));
        m = fmaxf(m, fmaxf(fmaxf(d.x, d.y), fmaxf(d.z, d.w)));
        gfp[i] = m;
    }
    __threadfence();                         // publish parts2 (+gfp)
    __syncthreads();
    if (t == 0) {
        atomicAdd(cnt, 1);
        while (__hip_atomic_load(cnt, __ATOMIC_ACQUIRE, __HIP_MEMORY_SCOPE_AGENT) < NBLK)
            __builtin_amdgcn_s_sleep(8);
    }
    __syncthreads();
    __threadfence();
    if (t < 16) {                            // S: f64, fixed chunk order (bit-identical)
        double S = 0.0;
        for (int c2 = 0; c2 < CH_; ++c2)
            S += (double)__hip_atomic_load(&parts2[((size_t)b * 32 + c2) * 32 + t],
                                           __ATOMIC_RELAXED, __HIP_MEMORY_SCOPE_AGENT);
        iSs[t] = (float)(1.0 / S);
    }
    __syncthreads();
    float iSr[16];
#pragma unroll
    for (int k2 = 0; k2 < 16; ++k2) iSr[k2] = iSs[k2];
    float acc[4][3];
#pragma unroll
    for (int kk = 0; kk < 4; ++kk)
#pragma unroll
        for (int d = 0; d < 3; ++d) acc[kk][d] = 0.0f;
    const float* xb = X + (size_t)b * N_ * 3;
#pragma unroll
    for (int it = 0; it < ITERS; ++it) {     // KPCD accumulate (scale-on-read)
        int nloc = it * 64 + (t >> 2);
        int n = ch * PTS + nloc;
        float x0 = xb[(size_t)n * 3 + 0];
        float x1 = xb[(size_t)n * 3 + 1];
        float x2 = xb[(size_t)n * 3 + 2];
#pragma unroll
        for (int kk = 0; kk < 4; ++kk) {
            float y = ybuf[4 * q + kk][nloc] * iSr[4 * q + kk];
            acc[kk][0] = fmaf(y, x0, acc[kk][0]);
            acc[kk][1] = fmaf(y, x1, acc[kk][1]);
            acc[kk][2] = fmaf(y, x2, acc[kk][2]);
        }
    }
#pragma unroll
    for (int o = 4; o <= 32; o <<= 1)
#pragma unroll
        for (int kk = 0; kk < 4; ++kk)
#pragma unroll
            for (int d = 0; d < 3; ++d) acc[kk][d] += __shfl_xor(acc[kk][d], o);
    if ((t & 63) < 4)
#pragma unroll
        for (int kk = 0; kk < 4; ++kk)
#pragma unroll
            for (int d = 0; d < 3; ++d) sa[w][q][kk][d] = acc[kk][d];
    __syncthreads();
    if (t < 48) {
        int k = t / 3, d = t - 3 * (t / 3);
        int qq = k >> 2, kk = k & 3;
        float s = sa[0][qq][kk][d] + sa[1][qq][kk][d] + sa[2][qq][kk][d] + sa[3][qq][kk][d];
        kpcdpart[(((size_t)b * 16 + k) * CH_ + ch) * 3 + d] = s;
    }
    // coalesced KPA writeback: wave writes contiguous 512B per row
#pragma unroll
    for (int k2 = 0; k2 < 16; ++k2) {
        float2 v2 = make_float2(ybuf[k2][2 * t] * iSr[k2], ybuf[k2][2 * t + 1] * iSr[k2]);
        *reinterpret_cast<float2*>(out_kpa + ((size_t)b * 16 + k2) * N_
                                   + (size_t)ch * PTS + 2 * t) = v2;
    }
}

// ========== shared mm+BN device helper (block = 32 rows x 8 slices, 256 thr) ==========
template<int INNER, int COLS, bool TRANSOUT>
__device__ __forceinline__ void mm_bn(const float* __restrict__ A, const float* __restrict__ W,
                                      const float* __restrict__ bias, const float* __restrict__ g,
                                      const float* __restrict__ bta, float* __restrict__ out,
                                      int col, int t, float (*red)[32]) {
    constexpr int PER = INNER / 8;
    int r = t & 31, s = t >> 5;
    const float4* a4 = (const float4*)(A + (size_t)r * INNER + s * PER);
    const float* wp = W + (size_t)(s * PER) * COLS + col;
    float acc = 0.0f;
#pragma unroll
    for (int j = 0; j < PER / 4; ++j) {
        float4 av = a4[j];
        acc = fmaf(av.x, wp[(size_t)(4 * j + 0) * COLS], acc);
        acc = fmaf(av.y, wp[(size_t)(4 * j + 1) * COLS], acc);
        acc = fmaf(av.z, wp[(size_t)(4 * j + 2) * COLS], acc);
        acc = fmaf(av.w, wp[(size_t)(4 * j + 3) * COLS], acc);
    }
    red[s][r] = acc;
    __syncthreads();
    if (s == 0) {
        float v = red[0][r];
#pragma unroll
        for (int qx = 1; qx < 8; ++qx) v += red[qx][r];
        v += bias[col];
        float mu = v;                               // BN over the 32 lanes (r = lane)
#pragma unroll
        for (int o = 1; o <= 16; o <<= 1) mu += __shfl_xor(mu, o);
        mu *= (1.0f / 32.0f);
        float dd = v - mu, sq = dd * dd;
#pragma unroll
        for (int o = 1; o <= 16; o <<= 1) sq += __shfl_xor(sq, o);
        float var = sq * (1.0f / 32.0f);
        float y = fmaxf(0.0f, g[col] * dd / sqrtf(var + 1e-5f) + bta[col]);
        if (TRANSOUT) out[(size_t)col * 32 + r] = y;      // block-private 128B line
        else          out[(size_t)r * COLS + col] = y;
    }
}

// ============ k2: RP (0..119) + mm1 (120..631) + LF (632..913) ============
__global__ __launch_bounds__(256) void k_mid(const float* __restrict__ kpcdpart,
                                             const float* __restrict__ emb,
                                             float* __restrict__ out_rp,
                                             float* __restrict__ out_kpcd, int total,
                                             const float* __restrict__ gfp,
                                             const float* __restrict__ ma_w1,
                                             const float* __restrict__ ma_b1,
                                             const float* __restrict__ bn1_g,
                                             const float* __restrict__ bn1_b,
                                             float* __restrict__ h1n,
                                             float* __restrict__ out_lf) {
    __shared__ double sKp[512 * 3];          // 12 KB
    __shared__ int sc[P_], soffs[P_];
    __shared__ float red[8][32];
    int t = threadIdx.x, p = blockIdx.x;
    if (p >= 632) {                          // ---- LF: 72000 elements ----
        int i = (p - 632) * 256 + t;
        if (i < 200 * P_ * 3) {
            int cc = i / (P_ * 3);
            int r = i - cc * (P_ * 3);
            int pp = r / 3, d = r - 3 * pp;
            out_lf[i] = emb[((size_t)pp * 200 + cc) * 3 + d];
        }
        return;
    }
    if (p >= 120) {                          // ---- MLP layer 1 ----
        mm_bn<1024, 512, false>(gfp, ma_w1, ma_b1, bn1_g, bn1_b, h1n, p - 120, t, red);
        return;
    }
    // ---- RP path: per-block kpcd reduce + counts + prefix (deterministic) ----
    for (int bk = t; bk < 512; bk += 256) {
        for (int d = 0; d < 3; ++d) {
            double s = 0.0;
            for (int ch = 0; ch < CH_; ++ch)
                s += (double)kpcdpart[((size_t)bk * CH_ + ch) * 3 + d];
            sKp[bk * 3 + d] = s;
        }
    }
    __syncthreads();
    if (t < P_) {
        int pi = 1, base = 0;
        while (t >= base + pi) { base += pi; ++pi; }
        int pj = t - base;
        double accd = 0.0;
        for (int b = 0; b < B_; ++b) {
            const double* A  = sKp + ((size_t)b * K_ + pi) * 3;
            const double* Bp = sKp + ((size_t)b * K_ + pj) * 3;
            double dx = A[0] - Bp[0], dy = A[1] - Bp[1], dz = A[2] - Bp[2];
            accd += sqrt(0.001 + dx * dx + dy * dy + dz * dz);
        }
        double dist = accd / 32.0;
        int c = (int)(dist / 0.01);
        sc[t] = min(200, max(15, c));
    }
    __syncthreads();
    if (t == 0) {
        int o = 0;
        for (int qx = 0; qx < P_; ++qx) { soffs[qx] = o; o += sc[qx]; }
    }
    __syncthreads();
    if (p == 0) {
        for (int i = t; i < 1536; i += 256) out_kpcd[i] = (float)sKp[i];
    }
    int pi = 1, base = 0;
    while (p >= base + pi) { base += pi; ++pi; }
    int pj = p - base;
    int c = sc[p], off = soffs[p];
    float delta = 1.0f / (float)(c - 1);
    int per_b = c * 3;
    int nitems = B_ * per_b;
    size_t total3 = (size_t)total * 3;
    for (int i = t; i < nitems; i += 256) {
        int b = i / per_b;
        int r = i - b * per_b;
        int ii = r / 3, d = r - 3 * ii;
        float f = (float)ii * delta;
        float A  = (float)sKp[((size_t)b * K_ + pi) * 3 + d];
        float Bv = (float)sKp[((size_t)b * K_ + pj) * 3 + d];
        out_rp[(size_t)b * total3 + (size_t)(off + ii) * 3 + d] =
            emb[((size_t)p * 200 + ii) * 3 + d] + (A * f + Bv * (1.0f - f));
    }
}

// ============ k3: mm2 (0..255, writes h2nT + ticket) + mmsig (256..375, spin) ============
__global__ __launch_bounds__(256) void k_tail(const float* __restrict__ h1n,
                                              const float* __restrict__ ma_w2,
                                              const float* __restrict__ ma_b2,
                                              const float* __restrict__ bn2_g,
                                              const float* __restrict__ bn2_b,
                                              float* __restrict__ h2nT,
                                              const float* __restrict__ mal_w,
                                              const float* __restrict__ mal_b,
                                              float* __restrict__ out_ma,
                                              int* __restrict__ cnt2) {
    __shared__ float red[8][32];
    int t = threadIdx.x, p = blockIdx.x;
    if (p < 256) {                           // ---- MLP layer 2, transposed store ----
        mm_bn<512, 256, true>(h1n, ma_w2, ma_b2, bn2_g, bn2_b, h2nT, p, t, red);
        __threadfence();
        __syncthreads();
        if (t == 0) atomicAdd(cnt2, 1);
        return;
    }
    if (t == 0) {                            // ---- mmsig: wait for all h2nT columns ----
        while (__hip_atomic_load(cnt2, __ATOMIC_ACQUIRE, __HIP_MEMORY_SCOPE_AGENT) < 256)
            __builtin_amdgcn_s_sleep(8);
    }
    __syncthreads();
    __threadfence();
    int col = p - 256;                       // 0..119
    int r = t & 31, s = t >> 5;              // 8 slices x 32 inner each
    float acc = 0.0f;
#pragma unroll
    for (int j = 0; j < 32; ++j) {
        float a = h2nT[(size_t)(s * 32 + j) * 32 + r];
        acc = fmaf(a, mal_w[(size_t)(s * 32 + j) * P_ + col], acc);
    }
    red[s][r] = acc;
    __syncthreads();
    if (s == 0) {
        float v = red[0][r];
#pragma unroll
        for (int qx = 1; qx < 8; ++qx) v += red[qx][r];
        v += mal_b[col];
        out_ma[(size_t)r * P_ + col] = 1.0f / (1.0f + expf(-v));
    }
}

extern "C" void kernel_launch(void* const* d_in, const int* in_sizes, int n_in,
                              void* d_out, int out_size, void* d_ws, size_t ws_size,
                              hipStream_t stream) {
    const float* input_x = (const float*)d_in[0];
    const float* KP      = (const float*)d_in[1];
    const float* GF      = (const float*)d_in[2];
    const float* ptl_w   = (const float*)d_in[3];
    const float* ma_w1   = (const float*)d_in[5];
    const float* ma_b1   = (const float*)d_in[6];
    const float* bn1_g   = (const float*)d_in[7];
    const float* bn1_b   = (const float*)d_in[8];
    const float* ma_w2   = (const float*)d_in[9];
    const float* ma_b2   = (const float*)d_in[10];
    const float* bn2_g   = (const float*)d_in[11];
    const float* bn2_b   = (const float*)d_in[12];
    const float* mal_w   = (const float*)d_in[13];
    const float* mal_b   = (const float*)d_in[14];
    const float* emb     = (const float*)d_in[15];
    // ptl_b (d_in[4]) provably cancels in the softmax over n — omitted.

    float* out = (float*)d_out;       // reference outputs are float32
    size_t rp_elems = (size_t)out_size - 8465984ull;
    int total = (int)(rp_elems / 96ull);
    float* out_rp   = out;
    float* out_kpcd = out + rp_elems;
    float* out_kpa  = out_kpcd + 1536;
    float* out_lf   = out_kpa + 8388608ull;
    float* out_ma   = out_lf + 72000;

    char* w = (char*)d_ws;
    float*  parts2   = (float*)(w + 1024);       // 131072 B (1024 x 32 floats, line-private)
    float*  kpcdpart = (float*)(w + 132096);     // 196608 B
    float*  gfp      = (float*)(w + 328704);     // 131072 B
    float*  h1n      = (float*)(w + 459776);     // 65536 B
    float*  h2nT     = (float*)(w + 525312);     // 32768 B (transposed, line-private rows)
    int*    cnt      = (int*)(w + 558080);       // 8 B (two counters)

    hipMemsetAsync(cnt, 0, 8, stream);           // reset tickets every call (replay-safe)

    k_fused<<<NBLK, 256, 0, stream>>>(KP, ptl_w, input_x, out_kpa, parts2, kpcdpart,
                                      GF, gfp, cnt);
    k_mid  <<<914, 256, 0, stream>>>(kpcdpart, emb, out_rp, out_kpcd, total,
                                     gfp, ma_w1, ma_b1, bn1_g, bn1_b, h1n, out_lf);
    k_tail <<<376, 256, 0, stream>>>(h1n, ma_w2, ma_b2, bn2_g, bn2_b, h2nT,
                                     mal_w, mal_b, out_ma, cnt + 1);
}

// Round 16
// 56.447 us; speedup vs baseline: 5.1268x; 5.1268x over previous
//
#include <hip/hip_runtime.h>

#define B_ 32
#define N_ 16384
#define K_ 16
#define P_ 120
#define CH_ 32          // chunks per (b) row
#define PTS 512         // points per chunk
#define ITERS 8         // PTS / 64 points-per-block-iteration

// ============ L1: chunk sums of exp(KP·W) -> parts (no KPA write)
//              + LF transpose (blocks 1024..1305) + GFP max (blocks 1306..1433) ============
// No max-subtraction: v ~ N(0,1), exp(v) in [4e-3, 300], f32-safe; softmax is shift-invariant.
// __expf (hw v_exp_f32) vs libm expf: ULP-level delta, consistent across both sweeps.
__global__ __launch_bounds__(256) void k_stats(const float* __restrict__ KP,
                                               const float* __restrict__ W,
                                               float* __restrict__ parts,
                                               const float* __restrict__ emb,
                                               float* __restrict__ out_lf,
                                               const float* __restrict__ GF,
                                               float* __restrict__ gfp) {
    int bid = blockIdx.x, t = threadIdx.x;
    if (bid >= 1024) {
        if (bid < 1306) {                   // LF: 72000 elements
            int i = (bid - 1024) * 256 + t;
            if (i < 200 * P_ * 3) {
                int cc = i / (P_ * 3);
                int r = i - cc * (P_ * 3);
                int p = r / 3, d = r - 3 * p;
                out_lf[i] = emb[((size_t)p * 200 + cc) * 3 + d];
            }
        } else {                            // GFP: 32768 points
            int i = (bid - 1306) * 256 + t;
            const float4* g = (const float4*)(GF + (size_t)i * 16);
            float4 a = g[0], b = g[1], c = g[2], d = g[3];
            float m = fmaxf(fmaxf(fmaxf(a.x, a.y), fmaxf(a.z, a.w)),
                            fmaxf(fmaxf(b.x, b.y), fmaxf(b.z, b.w)));
            m = fmaxf(m, fmaxf(fmaxf(c.x, c.y), fmaxf(c.z, c.w)));
            m = fmaxf(m, fmaxf(fmaxf(d.x, d.y), fmaxf(d.z, d.w)));
            gfp[i] = m;
        }
        return;
    }
    int ch = bid & (CH_ - 1), b = bid >> 5;
    int w = t >> 6, q = t & 3;
    __shared__ float Wl[256];
    Wl[t] = W[t];
    __syncthreads();
    float Wr[4][4][4];                       // [m][jj][kk] : W[4(q^m)+jj][4q+kk]
#pragma unroll
    for (int m = 0; m < 4; ++m)
#pragma unroll
        for (int jj = 0; jj < 4; ++jj)
#pragma unroll
            for (int kk = 0; kk < 4; ++kk)
                Wr[m][jj][kk] = Wl[(4 * (q ^ m) + jj) * 16 + 4 * q + kk];
    const float4* KP4 = (const float4*)KP;
    size_t base = (size_t)b * (N_ * 4) + (size_t)ch * (PTS * 4);
    float s4[4] = {0.0f, 0.0f, 0.0f, 0.0f};
#pragma unroll
    for (int it = 0; it < ITERS; ++it) {
        float4 a = KP4[base + it * 256 + t];
        float c0 = __shfl_xor(a.x, 1), c1 = __shfl_xor(a.y, 1), c2 = __shfl_xor(a.z, 1), c3 = __shfl_xor(a.w, 1);
        float d0 = __shfl_xor(a.x, 2), d1 = __shfl_xor(a.y, 2), d2 = __shfl_xor(a.z, 2), d3 = __shfl_xor(a.w, 2);
        float e0 = __shfl_xor(a.x, 3), e1 = __shfl_xor(a.y, 3), e2 = __shfl_xor(a.z, 3), e3 = __shfl_xor(a.w, 3);
#pragma unroll
        for (int kk = 0; kk < 4; ++kk) {
            float v = a.x * Wr[0][0][kk];
            v = fmaf(a.y, Wr[0][1][kk], v); v = fmaf(a.z, Wr[0][2][kk], v); v = fmaf(a.w, Wr[0][3][kk], v);
            v = fmaf(c0, Wr[1][0][kk], v);  v = fmaf(c1, Wr[1][1][kk], v);
            v = fmaf(c2, Wr[1][2][kk], v);  v = fmaf(c3, Wr[1][3][kk], v);
            v = fmaf(d0, Wr[2][0][kk], v);  v = fmaf(d1, Wr[2][1][kk], v);
            v = fmaf(d2, Wr[2][2][kk], v);  v = fmaf(d3, Wr[2][3][kk], v);
            v = fmaf(e0, Wr[3][0][kk], v);  v = fmaf(e1, Wr[3][1][kk], v);
            v = fmaf(e2, Wr[3][2][kk], v);  v = fmaf(e3, Wr[3][3][kk], v);
            s4[kk] += __expf(v);
        }
    }
#pragma unroll
    for (int o = 4; o <= 32; o <<= 1)
#pragma unroll
        for (int kk = 0; kk < 4; ++kk) s4[kk] += __shfl_xor(s4[kk], o);
    __shared__ float ss[4][4][4];            // [wave][q][kk]
    if ((t & 63) < 4)
#pragma unroll
        for (int kk = 0; kk < 4; ++kk) ss[w][q][kk] = s4[kk];
    __syncthreads();
    if (t < 16) {
        int qq = t >> 2, kk = t & 3;
        parts[((size_t)b * 16 + t) * CH_ + ch] =
            ss[0][qq][kk] + ss[1][qq][kk] + ss[2][qq][kk] + ss[3][qq][kk];
    }
}

// ========== shared mm+BN device helper (block = 32 rows x SLICES slices, 256 thr) ==========
template<int INNER, int COLS, int SLICES>
__device__ __forceinline__ void mm_bn(const float* __restrict__ A, const float* __restrict__ W,
                                      const float* __restrict__ bias, const float* __restrict__ g,
                                      const float* __restrict__ bta, float* __restrict__ out,
                                      int col, int t, float (*red)[32]) {
    constexpr int PER = INNER / SLICES;
    int r = t & 31, s = t >> 5;
    const float4* a4 = (const float4*)(A + (size_t)r * INNER + s * PER);
    const float* wp = W + (size_t)(s * PER) * COLS + col;
    float acc = 0.0f;
#pragma unroll
    for (int j = 0; j < PER / 4; ++j) {
        float4 av = a4[j];
        acc = fmaf(av.x, wp[(size_t)(4 * j + 0) * COLS], acc);
        acc = fmaf(av.y, wp[(size_t)(4 * j + 1) * COLS], acc);
        acc = fmaf(av.z, wp[(size_t)(4 * j + 2) * COLS], acc);
        acc = fmaf(av.w, wp[(size_t)(4 * j + 3) * COLS], acc);
    }
    red[s][r] = acc;
    __syncthreads();
    if (s == 0) {
        float v = red[0][r];
#pragma unroll
        for (int qx = 1; qx < SLICES; ++qx) v += red[qx][r];
        v += bias[col];
        float mu = v;                               // BN over the 32 lanes (r = lane)
#pragma unroll
        for (int o = 1; o <= 16; o <<= 1) mu += __shfl_xor(mu, o);
        mu *= (1.0f / 32.0f);
        float dd = v - mu, sq = dd * dd;
#pragma unroll
        for (int o = 1; o <= 16; o <<= 1) sq += __shfl_xor(sq, o);
        float var = sq * (1.0f / 32.0f);
        float y = g[col] * dd / sqrtf(var + 1e-5f) + bta[col];
        out[(size_t)r * COLS + col] = fmaxf(0.0f, y);
    }
}

#define YPAD 514        // 512 + 2 : store bank = (8q + 2kk + u) % 32 -> 2 lanes/bank (free)

// ============ L2: recompute ev, KPA = ev/S staged in LDS then coalesced write;
//              chunk-partial KPCD (blocks 0..1023) + MLP layer 1 (blocks 1024..1535) ============
__global__ __launch_bounds__(256) void k_apply(const float* __restrict__ KP,
                                               const float* __restrict__ W,
                                               const float* __restrict__ parts,
                                               const float* __restrict__ X,
                                               float* __restrict__ out_kpa,
                                               float* __restrict__ kpcdpart,
                                               const float* __restrict__ gfp,
                                               const float* __restrict__ ma_w1,
                                               const float* __restrict__ ma_b1,
                                               const float* __restrict__ bn1_g,
                                               const float* __restrict__ bn1_b,
                                               float* __restrict__ h1n) {
    __shared__ float pool[16 * YPAD];        // 32896 B: ybuf (compute) / red (mm) union
    __shared__ float Wl[256];
    __shared__ float iSs[16];
    __shared__ float sa[4][4][4][3];
    int bid = blockIdx.x, t = threadIdx.x;
    if (bid >= 1024) {
        mm_bn<1024, 512, 8>(gfp, ma_w1, ma_b1, bn1_g, bn1_b, h1n, bid - 1024, t,
                            (float(*)[32])pool);
        return;
    }
    float (*ybuf)[YPAD] = (float(*)[YPAD])pool;
    int ch = bid & (CH_ - 1), b = bid >> 5;
    int w = t >> 6, q = t & 3;
    Wl[t] = W[t];
    if (t < 16) {                            // combine 32 chunk sums (f64, fixed order)
        const float* ps = parts + ((size_t)b * 16 + t) * CH_;
        double S = 0.0;
        for (int c2 = 0; c2 < CH_; ++c2) S += (double)ps[c2];
        iSs[t] = (float)(1.0 / S);
    }
    __syncthreads();
    float Wr[4][4][4];
#pragma unroll
    for (int m = 0; m < 4; ++m)
#pragma unroll
        for (int jj = 0; jj < 4; ++jj)
#pragma unroll
            for (int kk = 0; kk < 4; ++kk)
                Wr[m][jj][kk] = Wl[(4 * (q ^ m) + jj) * 16 + 4 * q + kk];
    float iS[4];
#pragma unroll
    for (int kk = 0; kk < 4; ++kk) iS[kk] = iSs[4 * q + kk];
    const float4* KP4 = (const float4*)KP;
    size_t base = (size_t)b * (N_ * 4) + (size_t)ch * (PTS * 4);
    float acc[4][3];
#pragma unroll
    for (int kk = 0; kk < 4; ++kk)
#pragma unroll
        for (int d = 0; d < 3; ++d) acc[kk][d] = 0.0f;
    const float* xb = X + (size_t)b * N_ * 3;
#pragma unroll
    for (int it = 0; it < ITERS; ++it) {
        float4 a = KP4[base + it * 256 + t];
        float c0 = __shfl_xor(a.x, 1), c1 = __shfl_xor(a.y, 1), c2 = __shfl_xor(a.z, 1), c3 = __shfl_xor(a.w, 1);
        float d0 = __shfl_xor(a.x, 2), d1 = __shfl_xor(a.y, 2), d2 = __shfl_xor(a.z, 2), d3 = __shfl_xor(a.w, 2);
        float e0 = __shfl_xor(a.x, 3), e1 = __shfl_xor(a.y, 3), e2 = __shfl_xor(a.z, 3), e3 = __shfl_xor(a.w, 3);
        int nloc = it * 64 + (t >> 2);
        int n = ch * PTS + nloc;
        float x0 = xb[(size_t)n * 3 + 0];
        float x1 = xb[(size_t)n * 3 + 1];
        float x2 = xb[(size_t)n * 3 + 2];
#pragma unroll
        for (int kk = 0; kk < 4; ++kk) {
            float v = a.x * Wr[0][0][kk];
            v = fmaf(a.y, Wr[0][1][kk], v); v = fmaf(a.z, Wr[0][2][kk], v); v = fmaf(a.w, Wr[0][3][kk], v);
            v = fmaf(c0, Wr[1][0][kk], v);  v = fmaf(c1, Wr[1][1][kk], v);
            v = fmaf(c2, Wr[1][2][kk], v);  v = fmaf(c3, Wr[1][3][kk], v);
            v = fmaf(d0, Wr[2][0][kk], v);  v = fmaf(d1, Wr[2][1][kk], v);
            v = fmaf(d2, Wr[2][2][kk], v);  v = fmaf(d3, Wr[2][3][kk], v);
            v = fmaf(e0, Wr[3][0][kk], v);  v = fmaf(e1, Wr[3][1][kk], v);
            v = fmaf(e2, Wr[3][2][kk], v);  v = fmaf(e3, Wr[3][3][kk], v);
            float y = __expf(v) * iS[kk];
            ybuf[4 * q + kk][nloc] = y;      // 2-way bank aliasing only (free)
            acc[kk][0] = fmaf(y, x0, acc[kk][0]);
            acc[kk][1] = fmaf(y, x1, acc[kk][1]);
            acc[kk][2] = fmaf(y, x2, acc[kk][2]);
        }
    }
#pragma unroll
    for (int o = 4; o <= 32; o <<= 1)
#pragma unroll
        for (int kk = 0; kk < 4; ++kk)
#pragma unroll
            for (int d = 0; d < 3; ++d) acc[kk][d] += __shfl_xor(acc[kk][d], o);
    if ((t & 63) < 4)
#pragma unroll
        for (int kk = 0; kk < 4; ++kk)
#pragma unroll
            for (int d = 0; d < 3; ++d) sa[w][q][kk][d] = acc[kk][d];
    __syncthreads();                          // ybuf + sa complete
    if (t < 48) {
        int k = t / 3, d = t - 3 * (t / 3);
        int qq = k >> 2, kk = k & 3;
        float s = sa[0][qq][kk][d] + sa[1][qq][kk][d] + sa[2][qq][kk][d] + sa[3][qq][kk][d];
        kpcdpart[(((size_t)b * 16 + k) * CH_ + ch) * 3 + d] = s;
    }
    // coalesced KPA writeback: one row per iteration, wave writes contiguous 512B
#pragma unroll
    for (int k2 = 0; k2 < 16; ++k2) {
        float2 v2 = make_float2(ybuf[k2][2 * t], ybuf[k2][2 * t + 1]);
        *reinterpret_cast<float2*>(out_kpa + ((size_t)b * 16 + k2) * N_
                                   + (size_t)ch * PTS + 2 * t) = v2;
    }
}

// ============ L3: RP fill (blocks 0..119) + MLP layer 2 (blocks 120..375) ============
__global__ __launch_bounds__(256) void k_rp(const float* __restrict__ kpcdpart,
                                            const float* __restrict__ emb,
                                            float* __restrict__ out_rp,
                                            float* __restrict__ out_kpcd, int total,
                                            const float* __restrict__ h1n,
                                            const float* __restrict__ ma_w2,
                                            const float* __restrict__ ma_b2,
                                            const float* __restrict__ bn2_g,
                                            const float* __restrict__ bn2_b,
                                            float* __restrict__ h2n) {
    __shared__ double sKp[512 * 3];          // 12 KB
    __shared__ int sc[P_], soffs[P_];
    __shared__ float red[8][32];             // mm path
    int t = threadIdx.x, p = blockIdx.x;
    if (p >= 120) {                          // ---- MLP layer 2 ----
        mm_bn<512, 256, 8>(h1n, ma_w2, ma_b2, bn2_g, bn2_b, h2n, p - 120, t, red);
        return;
    }
    // ---- RP path: per-block kpcd reduce + counts + prefix (deterministic) ----
    for (int bk = t; bk < 512; bk += 256) {
        for (int d = 0; d < 3; ++d) {
            double s = 0.0;
            for (int ch = 0; ch < CH_; ++ch)
                s += (double)kpcdpart[((size_t)bk * CH_ + ch) * 3 + d];
            sKp[bk * 3 + d] = s;
        }
    }
    __syncthreads();
    if (t < P_) {
        int pi = 1, base = 0;
        while (t >= base + pi) { base += pi; ++pi; }
        int pj = t - base;
        double accd = 0.0;
        for (int b = 0; b < B_; ++b) {
            const double* A  = sKp + ((size_t)b * K_ + pi) * 3;
            const double* Bp = sKp + ((size_t)b * K_ + pj) * 3;
            double dx = A[0] - Bp[0], dy = A[1] - Bp[1], dz = A[2] - Bp[2];
            accd += sqrt(0.001 + dx * dx + dy * dy + dz * dz);
        }
        double dist = accd / 32.0;
        int c = (int)(dist / 0.01);
        sc[t] = min(200, max(15, c));
    }
    __syncthreads();
    if (t == 0) {
        int o = 0;
        for (int qx = 0; qx < P_; ++qx) { soffs[qx] = o; o += sc[qx]; }
    }
    __syncthreads();
    if (p == 0) {                            // block 0 also emits KPCD output
        for (int i = t; i < 1536; i += 256) out_kpcd[i] = (float)sKp[i];
    }
    int pi = 1, base = 0;
    while (p >= base + pi) { base += pi; ++pi; }
    int pj = p - base;
    int c = sc[p], off = soffs[p];
    float delta = 1.0f / (float)(c - 1);
    int per_b = c * 3;
    int nitems = B_ * per_b;
    size_t total3 = (size_t)total * 3;
    for (int i = t; i < nitems; i += 256) {
        int b = i / per_b;
        int r = i - b * per_b;
        int ii = r / 3, d = r - 3 * ii;
        float f = (float)ii * delta;
        float A  = (float)sKp[((size_t)b * K_ + pi) * 3 + d];
        float Bv = (float)sKp[((size_t)b * K_ + pj) * 3 + d];
        out_rp[(size_t)b * total3 + (size_t)(off + ii) * 3 + d] =
            emb[((size_t)p * 200 + ii) * 3 + d] + (A * f + Bv * (1.0f - f));
    }
}

// ========== L4: final matmul + sigmoid (block per column, inner sliced 4-way) ==========
template<int INNER, int COLS, int SLICES>
__global__ void k_mmsig(const float* __restrict__ A, const float* __restrict__ W,
                        const float* __restrict__ bias, float* __restrict__ out) {
    constexpr int PER = INNER / SLICES;
    int col = blockIdx.x;
    int t = threadIdx.x;
    int r = t & 31, s = t >> 5;
    const float4* a4 = (const float4*)(A + (size_t)r * INNER + s * PER);
    const float* wp = W + (size_t)(s * PER) * COLS + col;
    float acc = 0.0f;
#pragma unroll
    for (int j = 0; j < PER / 4; ++j) {
        float4 av = a4[j];
        acc = fmaf(av.x, wp[(size_t)(4 * j + 0) * COLS], acc);
        acc = fmaf(av.y, wp[(size_t)(4 * j + 1) * COLS], acc);
        acc = fmaf(av.z, wp[(size_t)(4 * j + 2) * COLS], acc);
        acc = fmaf(av.w, wp[(size_t)(4 * j + 3) * COLS], acc);
    }
    __shared__ float red[SLICES][32];
    red[s][r] = acc;
    __syncthreads();
    if (s == 0) {
        float v = red[0][r];
#pragma unroll
        for (int qx = 1; qx < SLICES; ++qx) v += red[qx][r];
        v += bias[col];
        out[(size_t)r * COLS + col] = 1.0f / (1.0f + __expf(-v));
    }
}

extern "C" void kernel_launch(void* const* d_in, const int* in_sizes, int n_in,
                              void* d_out, int out_size, void* d_ws, size_t ws_size,
                              hipStream_t stream) {
    const float* input_x = (const float*)d_in[0];
    const float* KP      = (const float*)d_in[1];
    const float* GF      = (const float*)d_in[2];
    const float* ptl_w   = (const float*)d_in[3];
    const float* ma_w1   = (const float*)d_in[5];
    const float* ma_b1   = (const float*)d_in[6];
    const float* bn1_g   = (const float*)d_in[7];
    const float* bn1_b   = (const float*)d_in[8];
    const float* ma_w2   = (const float*)d_in[9];
    const float* ma_b2   = (const float*)d_in[10];
    const float* bn2_g   = (const float*)d_in[11];
    const float* bn2_b   = (const float*)d_in[12];
    const float* mal_w   = (const float*)d_in[13];
    const float* mal_b   = (const float*)d_in[14];
    const float* emb     = (const float*)d_in[15];
    // ptl_b (d_in[4]) provably cancels in the softmax over n — omitted.

    float* out = (float*)d_out;       // reference outputs are float32
    size_t rp_elems = (size_t)out_size - 8465984ull;
    int total = (int)(rp_elems / 96ull);
    float* out_rp   = out;
    float* out_kpcd = out + rp_elems;
    float* out_kpa  = out_kpcd + 1536;
    float* out_lf   = out_kpa + 8388608ull;
    float* out_ma   = out_lf + 72000;

    char* w = (char*)d_ws;
    float*  parts    = (float*)(w + 1024);       // 65536 B
    float*  kpcdpart = (float*)(w + 66560);      // 196608 B
    float*  gfp      = (float*)(w + 263168);     // 131072 B
    float*  h1n      = (float*)(w + 394240);     // 65536 B
    float*  h2n      = (float*)(w + 459776);     // 32768 B (end 492544)

    k_stats<<<1434, 256, 0, stream>>>(KP, ptl_w, parts, emb, out_lf, GF, gfp);
    k_apply<<<1536, 256, 0, stream>>>(KP, ptl_w, parts, input_x, out_kpa, kpcdpart,
                                      gfp, ma_w1, ma_b1, bn1_g, bn1_b, h1n);
    k_rp   <<<376, 256, 0, stream>>>(kpcdpart, emb, out_rp, out_kpcd, total,
                                     h1n, ma_w2, ma_b2, bn2_g, bn2_b, h2n);
    k_mmsig<256, 120, 4><<<120, 128, 0, stream>>>(h2n, mal_w, mal_b, out_ma);
}